// Round 2
// baseline (305.848 us; speedup 1.0000x reference)
//
#include <hip/hip_runtime.h>

// BConv2d: x (32,32,256,256) f32 NCHW, W (32,32,3,3) f32 binarized to +-1,
// 3x3 'same' conv, out / sqrt(288).
//
// 9 accumulated GEMMs (one per tap) via mfma_f32_16x16x32_bf16.
// Block: one image, 8 output rows x 64 px x all 32 co. 8 waves =
// (4 row-pairs) x (2 co-halves). Stage 10 input rows (halo) to LDS ONCE,
// single barrier, compute, write. 4096 blocks -> 3 blocks/CU (LDS-capped).

typedef __attribute__((ext_vector_type(8))) short short8;
typedef __attribute__((ext_vector_type(4))) float f32x4;

__device__ __forceinline__ unsigned short f2bf(float f) {
    unsigned int u = __builtin_bit_cast(unsigned int, f);
    u += 0x7FFFu + ((u >> 16) & 1u);   // RNE
    return (unsigned short)(u >> 16);
}

__global__ __launch_bounds__(512, 6)
void bconv2d_kernel(const float* __restrict__ x, const float* __restrict__ wgt,
                    float* __restrict__ out) {
    // slot s (input row, 0..9), pixel p (0..65), ci-octet u (0..3)
    // 16B unit = s*264 + p*4 + (u ^ ((p>>1)&3))  -- bank-balanced for both
    // staging writes (p varies, u fixed) and fragment reads (p varies per lane).
    __shared__ short8 lds[10 * 264];   // 42240 B

    const int tid = threadIdx.x;
    const int gx0 = blockIdx.x * 64;   // x-strip
    const int Y0  = blockIdx.y * 8;    // 8-row strip
    const int n   = blockIdx.z;        // image

    const int l      = tid & 63;
    const int wv     = tid >> 6;       // wave 0..7
    const int rp     = (wv & 3) * 2;   // first output row of this wave's pair
    const int ch     = wv >> 2;        // co half 0..1
    const int lane15 = l & 15;
    const int lhi    = l >> 4;         // 0..3

    // ---- A fragments: sign(W) for all 9 taps, this wave's co-half ----
    // 16x16x32 A layout: lane holds A[row=l&15][k=(l>>4)*8+j]
    short8 afrag[3][3];
    {
        const int co  = ch * 16 + lane15;
        const int ci0 = lhi * 8;
        #pragma unroll
        for (int dy = 0; dy < 3; ++dy) {
            #pragma unroll
            for (int dx = 0; dx < 3; ++dx) {
                short8 a;
                #pragma unroll
                for (int j = 0; j < 8; ++j) {
                    float wval = wgt[((co * 32 + (ci0 + j)) * 3 + dy) * 3 + dx];
                    a[j] = (short)((wval > 0.0f) ? 0x3F80 : 0xBF80);  // +-1 bf16
                }
                afrag[dy][dx] = a;
            }
        }
    }

    // ---- stage 10 input rows (Y0-1 .. Y0+8), transpose NCHW -> [pix][ci] bf16
    for (int task = tid; task < 10 * 264; task += 512) {
        const int row = task / 264;            // slot 0..9
        const int rem = task - row * 264;
        const int u   = rem / 66;              // ci octet
        const int p   = rem - u * 66;          // pixel 0..65
        const int gy  = Y0 - 1 + row;
        const int gx  = gx0 - 1 + p;
        short8 v = (short8)0;
        if ((unsigned)gy < 256u && (unsigned)gx < 256u) {
            const float* src = x + (((size_t)n * 32 + u * 8) * 256 + gy) * 256 + gx;
            #pragma unroll
            for (int j = 0; j < 8; ++j)
                v[j] = (short)f2bf(src[(size_t)j * 65536]);
        }
        lds[row * 264 + p * 4 + (u ^ ((p >> 1) & 3))] = v;
    }
    __syncthreads();   // the only barrier

    // ---- compute: 2 rows x 4 px-tiles per wave; share B across the row pair
    f32x4 acc[2][4];
    #pragma unroll
    for (int rr = 0; rr < 2; ++rr)
        #pragma unroll
        for (int tp = 0; tp < 4; ++tp) acc[rr][tp] = (f32x4)0.0f;

    // output row r uses slots r..r+2 (slot = r + dy); pair rp,rp+1 -> slots rp..rp+3
    #pragma unroll
    for (int ss = 0; ss < 4; ++ss) {
        const int sbase = (rp + ss) * 264;
        #pragma unroll
        for (int dx = 0; dx < 3; ++dx) {
            #pragma unroll
            for (int tp = 0; tp < 4; ++tp) {
                const int p = tp * 16 + lane15 + dx;
                short8 b = lds[sbase + p * 4 + (lhi ^ ((p >> 1) & 3))];
                if (ss < 3)
                    acc[0][tp] = __builtin_amdgcn_mfma_f32_16x16x32_bf16(
                        afrag[ss][dx], b, acc[0][tp], 0, 0, 0);
                if (ss >= 1)
                    acc[1][tp] = __builtin_amdgcn_mfma_f32_16x16x32_bf16(
                        afrag[ss - 1][dx], b, acc[1][tp], 0, 0, 0);
            }
        }
    }

    // ---- write: D layout lane l reg q -> co_local=(l>>4)*4+q, px=l&15
    const float invdiv = 0.05892556509887896f;   // 1/sqrt(288)
    #pragma unroll
    for (int rr = 0; rr < 2; ++rr) {
        const int y = Y0 + rp + rr;
        #pragma unroll
        for (int tp = 0; tp < 4; ++tp) {
            #pragma unroll
            for (int q = 0; q < 4; ++q) {
                const int co = ch * 16 + lhi * 4 + q;
                out[(((size_t)n * 32 + co) * 256 + y) * 256 + gx0 + tp * 16 + lane15]
                    = acc[rr][tp][q] * invdiv;
            }
        }
    }
}

extern "C" void kernel_launch(void* const* d_in, const int* in_sizes, int n_in,
                              void* d_out, int out_size, void* d_ws, size_t ws_size,
                              hipStream_t stream) {
    const float* x   = (const float*)d_in[0];
    const float* wgt = (const float*)d_in[1];
    float* out = (float*)d_out;
    dim3 grid(4, 32, 32);   // x-strips, 8-row strips, images
    dim3 block(512);
    bconv2d_kernel<<<grid, block, 0, stream>>>(x, wgt, out);
}

// Round 3
// 274.485 us; speedup vs baseline: 1.1143x; 1.1143x over previous
//
#include <hip/hip_runtime.h>
#include <hip/hip_bf16.h>

// BConv2d: x (32,32,256,256) f32 NCHW, W (32,32,3,3) binarized to +-1,
// 3x3 'same' conv, out / sqrt(288).
//
// 9 accumulated GEMMs (one per tap) via mfma_f32_16x16x32_bf16.
// Block: one image, 64px x 32row strip, all 32 co. 8 waves = 4 rows x 2 co-halves.
// Rolling 8-row LDS window; stage 4 rows/iter with float4-vectorized loads and
// in-register transpose to ci-contiguous 16B LDS units. Grid 1024 -> 3 blocks/CU.

typedef __attribute__((ext_vector_type(8))) short short8;
typedef __attribute__((ext_vector_type(4))) float f32x4;

__device__ __forceinline__ short bf16s(float f) {
    unsigned int u = __builtin_bit_cast(unsigned int, f);
    u += 0x7FFFu + ((u >> 16) & 1u);   // RNE
    return (short)(u >> 16);
}

__global__ __launch_bounds__(512, 6)
void bconv2d_kernel(const float* __restrict__ x, const float* __restrict__ wgt,
                    float* __restrict__ out) {
    // unit (16B = 8 ci bf16) index = slot*264 + u*66 + px   (slot=row&7, u=ci/8)
    // quad writes: lanes stride 4 units -> banks fully tiled; b128 frag reads:
    // lanes 0..15 consecutive units -> banks fully tiled (b128-minimum, no conflict).
    __shared__ short8 lds[8 * 264];   // 33792 B

    const int tid = threadIdx.x;
    const int gx0 = blockIdx.x * 64;
    const int Y0  = blockIdx.y * 32;
    const int n   = blockIdx.z;

    const int l      = tid & 63;
    const int wv     = tid >> 6;
    const int r      = wv & 3;         // row within 4-row step
    const int ch     = wv >> 2;        // co half
    const int lane15 = l & 15;
    const int lhi    = l >> 4;

    // ---- A fragments: sign(W), this wave's co-half, all 9 taps ----
    short8 afrag[3][3];
    {
        const int co  = ch * 16 + lane15;
        const int ci0 = lhi * 8;
        #pragma unroll
        for (int dy = 0; dy < 3; ++dy)
            #pragma unroll
            for (int dx = 0; dx < 3; ++dx) {
                short8 a;
                #pragma unroll
                for (int j = 0; j < 8; ++j) {
                    float wval = wgt[((co * 32 + ci0 + j) * 3 + dy) * 3 + dx];
                    a[j] = (short)((wval > 0.0f) ? 0x3F80 : 0xBF80);
                }
                afrag[dy][dx] = a;
            }
    }

    const float* xn = x + (size_t)n * 32 * 65536;

    // stage rows [gy0v, gy0v+nrows): float4 px-loads, register transpose,
    // ci-contiguous LDS writes. Interior px 1..64 via quads, px 0/65 scalar edge.
    auto stage = [&](int gy0v, int nrows) {
        const int nq = nrows * 64;              // quad tasks: row x u(4) x q(16)
        const int nt = nq + nrows * 8;          // + edge: row x u(4) x side(2)
        for (int task = tid; task < nt; task += 512) {
            if (task < nq) {
                const int row = task >> 6;
                const int u   = (task >> 4) & 3;
                const int q   = task & 15;
                const int gy  = gy0v + row;
                short8 w[4] = {};
                if ((unsigned)gy < 256u) {
                    const float* src = xn + ((size_t)(u * 8) * 256 + gy) * 256 + gx0 + q * 4;
                    #pragma unroll
                    for (int j = 0; j < 8; ++j) {
                        f32x4 v = *(const f32x4*)(src + (size_t)j * 65536);
                        #pragma unroll
                        for (int t = 0; t < 4; ++t)
                            w[t][j] = bf16s(v[t]);
                    }
                }
                const int base = (gy & 7) * 264 + u * 66 + q * 4 + 1;
                #pragma unroll
                for (int t = 0; t < 4; ++t) lds[base + t] = w[t];
            } else {
                const int e    = task - nq;
                const int row  = e >> 3;
                const int u    = (e & 7) >> 1;
                const int side = e & 1;
                const int gy   = gy0v + row;
                const int p    = side ? 65 : 0;
                const int gx   = gx0 - 1 + p;
                short8 w = {};
                if ((unsigned)gy < 256u && (unsigned)gx < 256u) {
                    const float* src = xn + ((size_t)(u * 8) * 256 + gy) * 256 + gx;
                    #pragma unroll
                    for (int j = 0; j < 8; ++j) w[j] = bf16s(src[(size_t)j * 65536]);
                }
                lds[(gy & 7) * 264 + u * 66 + p] = w;
            }
        }
    };

    stage(Y0 - 1, 6);    // rows Y0-1 .. Y0+4
    __syncthreads();

    const float invdiv = 0.05892556509887896f;   // 1/sqrt(288)

    for (int i = 0; i < 8; ++i) {
        const int Y = Y0 + 4 * i;
        const int y = Y + r;

        f32x4 acc[4];
        #pragma unroll
        for (int tp = 0; tp < 4; ++tp) acc[tp] = (f32x4)0.0f;

        #pragma unroll
        for (int ss = 0; ss < 3; ++ss) {       // dy: input row y-1+ss
            const int sbase = ((y - 1 + ss) & 7) * 264 + lhi * 66 + lane15;
            #pragma unroll
            for (int dx = 0; dx < 3; ++dx)
                #pragma unroll
                for (int tp = 0; tp < 4; ++tp) {
                    short8 b = lds[sbase + tp * 16 + dx];
                    acc[tp] = __builtin_amdgcn_mfma_f32_16x16x32_bf16(
                        afrag[ss][dx], b, acc[tp], 0, 0, 0);
                }
        }

        __syncthreads();                 // readers done before slot overwrite
        if (i < 7) stage(Y + 5, 4);      // issue next 4 rows' loads first...

        // ...then the epilogue stores (overlap with staging latency).
        // D layout: lane l reg q -> co_local=(l>>4)*4+q, px=l&15
        #pragma unroll
        for (int tp = 0; tp < 4; ++tp)
            #pragma unroll
            for (int q = 0; q < 4; ++q) {
                const int co = ch * 16 + lhi * 4 + q;
                out[(((size_t)n * 32 + co) * 256 + y) * 256 + gx0 + tp * 16 + lane15]
                    = acc[tp][q] * invdiv;
            }
        __syncthreads();                 // staged rows visible
    }
}

extern "C" void kernel_launch(void* const* d_in, const int* in_sizes, int n_in,
                              void* d_out, int out_size, void* d_ws, size_t ws_size,
                              hipStream_t stream) {
    const float* x   = (const float*)d_in[0];
    const float* wgt = (const float*)d_in[1];
    float* out = (float*)d_out;
    dim3 grid(4, 8, 32);    // x-strips(64), y-strips(32 rows), images
    dim3 block(512);
    bconv2d_kernel<<<grid, block, 0, stream>>>(x, wgt, out);
}

// Round 4
// 150.266 us; speedup vs baseline: 2.0354x; 1.8267x over previous
//
#include <hip/hip_runtime.h>

// BConv2d: x (32,32,256,256) f32 NCHW, W (32,32,3,3) binarized to +-1,
// 3x3 'same' conv, out / sqrt(288).
//
// R1 base (proven clean traffic: 64px x 64row strips, 512 blocks, XOR-swizzled
// [slot][px][ci-octet] LDS, scalar-dword staging, stores-in-iter) + software
// pipeline: loads for stage s issued at iter s-2 into registers, ds_written at
// iter s-1, consumed at iters s-1/s. One barrier per iteration. 12-slot window.

typedef __attribute__((ext_vector_type(8))) short short8;
typedef __attribute__((ext_vector_type(4))) float f32x4;

__device__ __forceinline__ short bf16s(float f) {
    unsigned int u = __builtin_bit_cast(unsigned int, f);
    u += 0x7FFFu + ((u >> 16) & 1u);   // RNE
    return (short)(u >> 16);
}

__global__ __launch_bounds__(512, 4)
void bconv2d_kernel(const float* __restrict__ x, const float* __restrict__ wgt,
                    float* __restrict__ out) {
    // unit = slot*264 + pl*4 + (u ^ ((pl>>1)&3)); slot = row_local % 12,
    // row_local = gy - Y0 + 1; pl = 0..65 (px gx0-1 .. gx0+64).
    // Stage s = rows row_local 4s..4s+3. R1-proven bank-clean for both
    // px-consecutive b128 writes and fragment b128 reads.
    __shared__ short8 lds[12 * 264];   // 50688 B

    const int tid = threadIdx.x;
    const int gx0 = blockIdx.x * 64;
    const int Y0  = blockIdx.y * 64;
    const int n   = blockIdx.z;

    const int l      = tid & 63;
    const int wv     = tid >> 6;
    const int r      = wv & 3;         // row within 4-row step
    const int ch     = wv >> 2;        // co half
    const int lane15 = l & 15;
    const int lhi    = l >> 4;

    // ---- A fragments: sign(W), this wave's co-half, all 9 taps ----
    short8 afrag[3][3];
    {
        const int co  = ch * 16 + lane15;
        const int ci0 = lhi * 8;
        #pragma unroll
        for (int dy = 0; dy < 3; ++dy)
            #pragma unroll
            for (int dx = 0; dx < 3; ++dx) {
                short8 a;
                #pragma unroll
                for (int j = 0; j < 8; ++j) {
                    float wval = wgt[((co * 32 + ci0 + j) * 3 + dy) * 3 + dx];
                    a[j] = (short)((wval > 0.0f) ? 0x3F80 : 0xBF80);
                }
                afrag[dy][dx] = a;
            }
    }

    const float* xn = x + (size_t)n * 32 * 65536;

    // per-thread staging ownership (fixed across stages):
    //   interior task t = tid + k*512, k=0,1:  rr=t>>8, u=(t>>6)&3, pl=1+(t&63)
    //   edge (tid>=480): e=tid-480: rr=e>>3, u=(e>>1)&3, side=e&1 -> pl 0 or 65
    float rg[2][8];     // pending interior loads (f32)
    float re[8];        // pending edge loads (wave 7 upper half only)

    auto stage_load = [&](int s) {
        const int bg = Y0 + 4 * s - 1;   // gy of row_local 4s
        #pragma unroll
        for (int k = 0; k < 2; ++k) {
            const int t  = tid + k * 512;
            const int rr = t >> 8;
            const int u  = (t >> 6) & 3;
            const int pl = 1 + (t & 63);
            const int gy = bg + rr;
            if ((unsigned)gy < 256u) {
                const float* src = xn + ((size_t)(u * 8) * 256 + gy) * 256 + gx0 + (pl - 1);
                #pragma unroll
                for (int j = 0; j < 8; ++j) rg[k][j] = src[(size_t)j * 65536];
            } else {
                #pragma unroll
                for (int j = 0; j < 8; ++j) rg[k][j] = 0.0f;
            }
        }
        if (tid >= 480) {
            const int e    = tid - 480;
            const int rr   = e >> 3;
            const int u    = (e >> 1) & 3;
            const int side = e & 1;
            const int gy   = bg + rr;
            const int gx   = side ? gx0 + 64 : gx0 - 1;
            if ((unsigned)gy < 256u && (unsigned)gx < 256u) {
                const float* src = xn + ((size_t)(u * 8) * 256 + gy) * 256 + gx;
                #pragma unroll
                for (int j = 0; j < 8; ++j) re[j] = src[(size_t)j * 65536];
            } else {
                #pragma unroll
                for (int j = 0; j < 8; ++j) re[j] = 0.0f;
            }
        }
    };

    auto stage_write = [&](int s) {
        const int slot0 = 4 * (s % 3);     // R(s) occupies slots 4(s%3)..+3
        #pragma unroll
        for (int k = 0; k < 2; ++k) {
            const int t  = tid + k * 512;
            const int rr = t >> 8;
            const int u  = (t >> 6) & 3;
            const int pl = 1 + (t & 63);
            short8 v;
            #pragma unroll
            for (int j = 0; j < 8; ++j) v[j] = bf16s(rg[k][j]);
            lds[(slot0 + rr) * 264 + pl * 4 + (u ^ ((pl >> 1) & 3))] = v;
        }
        if (tid >= 480) {
            const int e    = tid - 480;
            const int rr   = e >> 3;
            const int u    = (e >> 1) & 3;
            const int side = e & 1;
            const int pl   = side ? 65 : 0;
            short8 v;
            #pragma unroll
            for (int j = 0; j < 8; ++j) v[j] = bf16s(re[j]);
            lds[(slot0 + rr) * 264 + pl * 4 + (u ^ ((pl >> 1) & 3))] = v;
        }
    };

    // ---- prologue: R(0) loaded+written; R(1) loaded (pending) ----
    stage_load(0);
    stage_write(0);      // per-wave vmcnt wait only
    stage_load(1);

    const float invdiv = 0.05892556509887896f;   // 1/sqrt(288)
    int i3 = 0;                                   // i % 3

    for (int i = 0; i < 16; ++i) {
        // (a) pending regs -> LDS (vmcnt for loads issued one iter ago)
        stage_write(i + 1);
        // (b) single barrier: R(i+1) visible, prior readers done
        __syncthreads();
        // (c) issue next stage's loads; hidden under compute+stores
        if (i < 15) stage_load(i + 2);

        // (d) compute rows y = Y0 + 4i + r
        f32x4 acc[4];
        #pragma unroll
        for (int tp = 0; tp < 4; ++tp) acc[tp] = (f32x4)0.0f;

        #pragma unroll
        for (int ss = 0; ss < 3; ++ss) {           // input row y-1+ss
            int m = 4 * i3 + r + ss;               // row_local % 12
            if (m >= 12) m -= 12;
            const int sbase = m * 264;
            #pragma unroll
            for (int dx = 0; dx < 3; ++dx)
                #pragma unroll
                for (int tp = 0; tp < 4; ++tp) {
                    const int pl = tp * 16 + lane15 + dx;
                    short8 b = lds[sbase + pl * 4 + (lhi ^ ((pl >> 1) & 3))];
                    acc[tp] = __builtin_amdgcn_mfma_f32_16x16x32_bf16(
                        afrag[ss][dx], b, acc[tp], 0, 0, 0);
                }
        }

        // (e) stores (R1-identical pattern)
        const int y = Y0 + 4 * i + r;
        #pragma unroll
        for (int tp = 0; tp < 4; ++tp)
            #pragma unroll
            for (int q = 0; q < 4; ++q) {
                const int co = ch * 16 + lhi * 4 + q;
                out[(((size_t)n * 32 + co) * 256 + y) * 256 + gx0 + tp * 16 + lane15]
                    = acc[tp][q] * invdiv;
            }

        i3 = (i3 == 2) ? 0 : i3 + 1;
    }
}

extern "C" void kernel_launch(void* const* d_in, const int* in_sizes, int n_in,
                              void* d_out, int out_size, void* d_ws, size_t ws_size,
                              hipStream_t stream) {
    const float* x   = (const float*)d_in[0];
    const float* wgt = (const float*)d_in[1];
    float* out = (float*)d_out;
    (void)d_ws; (void)ws_size;
    dim3 grid(4, 4, 32);    // 64px x-strips, 64-row y-strips, images
    dim3 block(512);
    bconv2d_kernel<<<grid, block, 0, stream>>>(x, wgt, out);
}